// Round 1
// baseline (2574.744 us; speedup 1.0000x reference)
//
#include <hip/hip_runtime.h>

#define T_STEPS 365
#define BATCH   2048
#define INP     9
#define HID     50
#define G4      200    // 4*HID gate rows
#define B_BLK   8      // batch elements per block
#define HPAD    52     // hidden padded to multiple of 4
#define IPAD    12     // input padded to multiple of 4
#define NTHREADS 256

__device__ __forceinline__ float sigmoid_(float x) {
    x = fminf(fmaxf(x, -30.f), 30.f);
    return __fdividef(1.f, 1.f + __expf(-x));
}
__device__ __forceinline__ float tanh_(float x) {
    x = fminf(fmaxf(x, -15.f), 15.f);
    float e = __expf(2.f * x);
    return __fdividef(e - 1.f, e + 1.f);
}

// One block = 8 batch elements, full 365-step scan of both LSTM layers + FC.
// Threads 0..199 each own one gate row (weights in registers, ~168 VGPRs).
// h/c state and gate handoff live in LDS; all gate-phase LDS reads are
// wave-uniform broadcasts (conflict-free).
__global__ __launch_bounds__(NTHREADS, 1)
void lstm_fused(const float* __restrict__ x,
                const float* __restrict__ w_ih0, const float* __restrict__ w_hh0,
                const float* __restrict__ b_ih0, const float* __restrict__ b_hh0,
                const float* __restrict__ w_ih1, const float* __restrict__ w_hh1,
                const float* __restrict__ b_ih1, const float* __restrict__ b_hh1,
                const float* __restrict__ fc_w, const float* __restrict__ fc_b,
                float* __restrict__ out)
{
    __shared__ float H0[B_BLK][HPAD];      // layer0 hidden state
    __shared__ float H1[B_BLK][HPAD];      // layer1 hidden state
    __shared__ float G [B_BLK][G4];        // gate pre-activations (reused l0/l1)
    __shared__ float XS[2][B_BLK][IPAD];   // double-buffered x staging
    __shared__ float FCW[HPAD];

    const int t  = threadIdx.x;
    const int b0 = blockIdx.x * B_BLK;

    // ---- weights into registers (thread t < 200 owns gate row t) ----
    const int row = (t < G4) ? t : (G4 - 1);
    float wi0[IPAD], wh0[HPAD], wi1[HPAD], wh1[HPAD];
    #pragma unroll
    for (int j = 0; j < IPAD; ++j) wi0[j] = (j < INP) ? w_ih0[row*INP + j] : 0.f;
    #pragma unroll
    for (int j = 0; j < HPAD; ++j) wh0[j] = (j < HID) ? w_hh0[row*HID + j] : 0.f;
    #pragma unroll
    for (int j = 0; j < HPAD; ++j) wi1[j] = (j < HID) ? w_ih1[row*HID + j] : 0.f;
    #pragma unroll
    for (int j = 0; j < HPAD; ++j) wh1[j] = (j < HID) ? w_hh1[row*HID + j] : 0.f;
    const float bias0 = b_ih0[row] + b_hh0[row];
    const float bias1 = b_ih1[row] + b_hh1[row];
    const float fcb   = fc_b[0];

    // ---- init LDS ----
    for (int i = t; i < B_BLK*HPAD; i += NTHREADS) {
        (&H0[0][0])[i] = 0.f;
        (&H1[0][0])[i] = 0.f;
    }
    for (int i = t; i < 2*B_BLK*IPAD; i += NTHREADS) (&XS[0][0][0])[i] = 0.f;
    if (t < HPAD) FCW[t] = (t < HID) ? fc_w[t] : 0.f;
    if (t < B_BLK*INP) {  // stage x[0]
        int bb = t / INP, j = t % INP;
        XS[0][bb][j] = x[((size_t)0 * BATCH + b0 + bb) * INP + j];
    }

    // elementwise-update mapping: thread t owns state idx=t, and idx=t+256 if t<144
    const int uA = t % HID,            bA = t / HID;
    const int idxB = t + NTHREADS;
    const int uB = idxB % HID,         bB = idxB / HID;
    const bool hasB = (idxB < B_BLK * HID);
    // x prefetch loaders: threads 144..215 (one value each)
    const bool xldr = (t >= 144 && t < 144 + B_BLK*INP);
    const int xu = t - 144, xbb = xu / INP, xj = xu % INP;

    float c0A = 0.f, c0B = 0.f, c1A = 0.f, c1B = 0.f;

    __syncthreads();

    for (int step = 0; step < T_STEPS; ++step) {
        const int cur = step & 1, nxt = cur ^ 1;

        // prefetch next step's x slice into registers (latency hidden by phases 1-3)
        float xpre = 0.f;
        if (xldr && step + 1 < T_STEPS)
            xpre = x[((size_t)(step+1) * BATCH + b0 + xbb) * INP + xj];

        // ---- phase 1: layer0 gates (t<200); FC of previous step (t=200..207) ----
        if (t < G4) {
            float acc[B_BLK];
            #pragma unroll
            for (int bb = 0; bb < B_BLK; ++bb) acc[bb] = bias0;
            #pragma unroll
            for (int j = 0; j < IPAD; j += 4) {
                #pragma unroll
                for (int bb = 0; bb < B_BLK; ++bb) {
                    float4 v = *(const float4*)&XS[cur][bb][j];
                    acc[bb] += wi0[j]*v.x + wi0[j+1]*v.y + wi0[j+2]*v.z + wi0[j+3]*v.w;
                }
            }
            #pragma unroll
            for (int j = 0; j < HPAD; j += 4) {
                #pragma unroll
                for (int bb = 0; bb < B_BLK; ++bb) {
                    float4 v = *(const float4*)&H0[bb][j];
                    acc[bb] += wh0[j]*v.x + wh0[j+1]*v.y + wh0[j+2]*v.z + wh0[j+3]*v.w;
                }
            }
            #pragma unroll
            for (int bb = 0; bb < B_BLK; ++bb) G[bb][t] = acc[bb];
        } else if (t < G4 + B_BLK && step > 0) {
            const int bb = t - G4;       // FC head for step-1 (H1 still holds h1[step-1])
            float s = fcb;
            #pragma unroll
            for (int j = 0; j < HPAD; j += 4) {
                float4 hv = *(const float4*)&H1[bb][j];
                float4 wv = *(const float4*)&FCW[j];
                s += wv.x*hv.x + wv.y*hv.y + wv.z*hv.z + wv.w*hv.w;
            }
            out[(size_t)(step-1) * BATCH + b0 + bb] = s;
        }
        __syncthreads();

        // ---- phase 2: layer0 elementwise update ----
        {
            float gi = sigmoid_(G[bA][uA]);
            float gf = sigmoid_(G[bA][uA +   HID]);
            float gg = tanh_   (G[bA][uA + 2*HID]);
            float go = sigmoid_(G[bA][uA + 3*HID]);
            c0A = gf * c0A + gi * gg;
            H0[bA][uA] = go * tanh_(c0A);
            if (hasB) {
                float gi2 = sigmoid_(G[bB][uB]);
                float gf2 = sigmoid_(G[bB][uB +   HID]);
                float gg2 = tanh_   (G[bB][uB + 2*HID]);
                float go2 = sigmoid_(G[bB][uB + 3*HID]);
                c0B = gf2 * c0B + gi2 * gg2;
                H0[bB][uB] = go2 * tanh_(c0B);
            }
        }
        __syncthreads();

        // ---- phase 3: layer1 gates ----
        if (t < G4) {
            float acc[B_BLK];
            #pragma unroll
            for (int bb = 0; bb < B_BLK; ++bb) acc[bb] = bias1;
            #pragma unroll
            for (int j = 0; j < HPAD; j += 4) {
                #pragma unroll
                for (int bb = 0; bb < B_BLK; ++bb) {
                    float4 v = *(const float4*)&H0[bb][j];
                    acc[bb] += wi1[j]*v.x + wi1[j+1]*v.y + wi1[j+2]*v.z + wi1[j+3]*v.w;
                }
            }
            #pragma unroll
            for (int j = 0; j < HPAD; j += 4) {
                #pragma unroll
                for (int bb = 0; bb < B_BLK; ++bb) {
                    float4 v = *(const float4*)&H1[bb][j];
                    acc[bb] += wh1[j]*v.x + wh1[j+1]*v.y + wh1[j+2]*v.z + wh1[j+3]*v.w;
                }
            }
            #pragma unroll
            for (int bb = 0; bb < B_BLK; ++bb) G[bb][t] = acc[bb];
        }
        __syncthreads();

        // ---- phase 4: layer1 elementwise update + x-stage write ----
        {
            float gi = sigmoid_(G[bA][uA]);
            float gf = sigmoid_(G[bA][uA +   HID]);
            float gg = tanh_   (G[bA][uA + 2*HID]);
            float go = sigmoid_(G[bA][uA + 3*HID]);
            c1A = gf * c1A + gi * gg;
            H1[bA][uA] = go * tanh_(c1A);
            if (hasB) {
                float gi2 = sigmoid_(G[bB][uB]);
                float gf2 = sigmoid_(G[bB][uB +   HID]);
                float gg2 = tanh_   (G[bB][uB + 2*HID]);
                float go2 = sigmoid_(G[bB][uB + 3*HID]);
                c1B = gf2 * c1B + gi2 * gg2;
                H1[bB][uB] = go2 * tanh_(c1B);
            }
            if (xldr) XS[nxt][xbb][xj] = xpre;
        }
        __syncthreads();
    }

    // ---- epilogue: FC for the last step ----
    if (t < B_BLK) {
        float s = fcb;
        #pragma unroll
        for (int j = 0; j < HPAD; j += 4) {
            float4 hv = *(const float4*)&H1[t][j];
            float4 wv = *(const float4*)&FCW[j];
            s += wv.x*hv.x + wv.y*hv.y + wv.z*hv.z + wv.w*hv.w;
        }
        out[(size_t)(T_STEPS-1) * BATCH + b0 + t] = s;
    }
}

extern "C" void kernel_launch(void* const* d_in, const int* in_sizes, int n_in,
                              void* d_out, int out_size, void* d_ws, size_t ws_size,
                              hipStream_t stream) {
    const float* x     = (const float*)d_in[0];
    const float* w_ih0 = (const float*)d_in[1];
    const float* w_hh0 = (const float*)d_in[2];
    const float* b_ih0 = (const float*)d_in[3];
    const float* b_hh0 = (const float*)d_in[4];
    const float* w_ih1 = (const float*)d_in[5];
    const float* w_hh1 = (const float*)d_in[6];
    const float* b_ih1 = (const float*)d_in[7];
    const float* b_hh1 = (const float*)d_in[8];
    const float* fc_w  = (const float*)d_in[9];
    const float* fc_b  = (const float*)d_in[10];
    float* out = (float*)d_out;

    lstm_fused<<<dim3(BATCH / B_BLK), dim3(NTHREADS), 0, stream>>>(
        x, w_ih0, w_hh0, b_ih0, b_hh0,
        w_ih1, w_hh1, b_ih1, b_hh1, fc_w, fc_b, out);
}

// Round 2
// 1790.620 us; speedup vs baseline: 1.4379x; 1.4379x over previous
//
#include <hip/hip_runtime.h>

#define T_STEPS 365
#define BATCH   2048
#define INP     9
#define HID     50
#define G4      200    // 4*HID gate rows
#define B_BLK   4      // batch elements per block
#define HPAD    56     // hidden padded: two halves of 28
#define KH      28     // per-thread k-half for hidden dims
#define IPAD    12     // input padded: two halves of 6
#define IH      6      // per-thread k-half for input dim
#define NT      512
#define NGT     400    // gate threads: 2 per gate row

__device__ __forceinline__ float sigmoid_(float x) {
    x = fminf(fmaxf(x, -30.f), 30.f);
    return __fdividef(1.f, 1.f + __expf(-x));
}
__device__ __forceinline__ float tanh_(float x) {
    x = fminf(fmaxf(x, -15.f), 15.f);
    float e = __expf(2.f * x);
    return __fdividef(e - 1.f, e + 1.f);
}

// One block = 4 batch elements, 512 threads (8 waves), full 365-step scan.
// Gate rows are split across thread PAIRS (t=2r: k<28, t=2r+1: k>=28) so the
// per-thread weight footprint (90 floats) fits the 128-VGPR budget enforced by
// __launch_bounds__(512,4) -> weights stay register-resident, and the 512-block
// grid gives 2 blocks/CU = 4 waves/SIMD of latency hiding.
__global__ __launch_bounds__(NT, 4)
void lstm_fused(const float* __restrict__ x,
                const float* __restrict__ w_ih0, const float* __restrict__ w_hh0,
                const float* __restrict__ b_ih0, const float* __restrict__ b_hh0,
                const float* __restrict__ w_ih1, const float* __restrict__ w_hh1,
                const float* __restrict__ b_ih1, const float* __restrict__ b_hh1,
                const float* __restrict__ fc_w, const float* __restrict__ fc_b,
                float* __restrict__ out)
{
    __shared__ __align__(16) float H0[B_BLK][HPAD];     // layer0 hidden
    __shared__ __align__(16) float H1[B_BLK][HPAD];     // layer1 hidden
    __shared__ __align__(16) float G [B_BLK][G4];       // gate pre-activations
    __shared__ __align__(16) float XS[2][B_BLK][IPAD];  // double-buffered x
    __shared__ __align__(16) float FCW[HPAD];

    const int t  = threadIdx.x;
    const int b0 = blockIdx.x * B_BLK;

    // ---- gate-thread identity: pair (2r, 2r+1) splits row r's k-range ----
    const int r    = (t < NGT) ? (t >> 1) : 0;
    const int half = t & 1;
    const int ko   = half * KH;   // hidden k-offset
    const int io   = half * IH;   // input  k-offset

    // ---- weights into registers: 6 + 3*28 = 90 floats ----
    float wi0r[IH], wh0r[KH], wi1r[KH], wh1r[KH];
    #pragma unroll
    for (int j = 0; j < IH; ++j) wi0r[j] = (io + j < INP) ? w_ih0[r*INP + io + j] : 0.f;
    #pragma unroll
    for (int j = 0; j < KH; ++j) wh0r[j] = (ko + j < HID) ? w_hh0[r*HID + ko + j] : 0.f;
    #pragma unroll
    for (int j = 0; j < KH; ++j) wi1r[j] = (ko + j < HID) ? w_ih1[r*HID + ko + j] : 0.f;
    #pragma unroll
    for (int j = 0; j < KH; ++j) wh1r[j] = (ko + j < HID) ? w_hh1[r*HID + ko + j] : 0.f;
    const float bias0 = half ? 0.f : (b_ih0[r] + b_hh0[r]);  // bias counted once per pair
    const float bias1 = half ? 0.f : (b_ih1[r] + b_hh1[r]);
    const float fcb   = fc_b[0];

    // ---- elementwise-update mapping: thread t<200 owns state (ubb, uu) ----
    const int ubb = t / HID;
    const int uu  = t - ubb * HID;
    float c0 = 0.f, c1 = 0.f;

    // ---- x prefetch loaders: threads 408..443 (one value each) ----
    const bool xldr = (t >= 408 && t < 408 + B_BLK * INP);
    const int xu  = xldr ? (t - 408) : 0;
    const int xbb = xu / INP, xj = xu - xbb * INP;

    // ---- init LDS ----
    for (int i = t; i < B_BLK*HPAD; i += NT) {
        (&H0[0][0])[i] = 0.f;
        (&H1[0][0])[i] = 0.f;
    }
    for (int i = t; i < 2*B_BLK*IPAD; i += NT) (&XS[0][0][0])[i] = 0.f;
    if (t < HPAD) FCW[t] = (t < HID) ? fc_w[t] : 0.f;
    if (t < B_BLK*INP) {  // stage x[0]
        int bb = t / INP, j = t - bb*INP;
        XS[0][bb][j] = x[(size_t)(b0 + bb) * INP + j];
    }
    __syncthreads();

    for (int step = 0; step < T_STEPS; ++step) {
        const int cur = step & 1, nxt = cur ^ 1;

        // prefetch next x slice (latency hidden under phases 1-3)
        float xpre = 0.f;
        if (xldr && step + 1 < T_STEPS)
            xpre = x[((size_t)(step+1) * BATCH + b0 + xbb) * INP + xj];

        // ---- phase 1: layer0 gates; FC head of step-1 on threads 448..451 ----
        if (t < NGT) {
            float acc[B_BLK];
            #pragma unroll
            for (int bb = 0; bb < B_BLK; ++bb) acc[bb] = bias0;
            #pragma unroll
            for (int bb = 0; bb < B_BLK; ++bb) {
                const float* xp = &XS[cur][bb][io];
                acc[bb] += wi0r[0]*xp[0] + wi0r[1]*xp[1] + wi0r[2]*xp[2]
                         + wi0r[3]*xp[3] + wi0r[4]*xp[4] + wi0r[5]*xp[5];
            }
            #pragma unroll
            for (int j = 0; j < KH; j += 4) {
                #pragma unroll
                for (int bb = 0; bb < B_BLK; ++bb) {
                    float4 v = *(const float4*)&H0[bb][ko + j];
                    acc[bb] += wh0r[j]*v.x + wh0r[j+1]*v.y + wh0r[j+2]*v.z + wh0r[j+3]*v.w;
                }
            }
            #pragma unroll
            for (int bb = 0; bb < B_BLK; ++bb) acc[bb] += __shfl_xor(acc[bb], 1);
            if (!half) {
                #pragma unroll
                for (int bb = 0; bb < B_BLK; ++bb) G[bb][r] = acc[bb];
            }
        } else if (t >= 448 && t < 448 + B_BLK && step > 0) {
            const int bb = t - 448;   // FC for step-1 (H1 holds h1[step-1])
            float s = fcb;
            #pragma unroll
            for (int j = 0; j < HPAD; j += 4) {
                float4 hv = *(const float4*)&H1[bb][j];
                float4 wv = *(const float4*)&FCW[j];
                s += wv.x*hv.x + wv.y*hv.y + wv.z*hv.z + wv.w*hv.w;
            }
            out[(size_t)(step-1) * BATCH + b0 + bb] = s;
        }
        __syncthreads();

        // ---- phase 2: layer0 elementwise update (t<200, one element each) ----
        if (t < G4) {
            float gi = sigmoid_(G[ubb][uu]);
            float gf = sigmoid_(G[ubb][uu +   HID]);
            float gg = tanh_   (G[ubb][uu + 2*HID]);
            float go = sigmoid_(G[ubb][uu + 3*HID]);
            c0 = gf * c0 + gi * gg;
            H0[ubb][uu] = go * tanh_(c0);
        }
        __syncthreads();

        // ---- phase 3: layer1 gates ----
        if (t < NGT) {
            float acc[B_BLK];
            #pragma unroll
            for (int bb = 0; bb < B_BLK; ++bb) acc[bb] = bias1;
            #pragma unroll
            for (int j = 0; j < KH; j += 4) {
                #pragma unroll
                for (int bb = 0; bb < B_BLK; ++bb) {
                    float4 v = *(const float4*)&H0[bb][ko + j];
                    acc[bb] += wi1r[j]*v.x + wi1r[j+1]*v.y + wi1r[j+2]*v.z + wi1r[j+3]*v.w;
                }
            }
            #pragma unroll
            for (int j = 0; j < KH; j += 4) {
                #pragma unroll
                for (int bb = 0; bb < B_BLK; ++bb) {
                    float4 v = *(const float4*)&H1[bb][ko + j];
                    acc[bb] += wh1r[j]*v.x + wh1r[j+1]*v.y + wh1r[j+2]*v.z + wh1r[j+3]*v.w;
                }
            }
            #pragma unroll
            for (int bb = 0; bb < B_BLK; ++bb) acc[bb] += __shfl_xor(acc[bb], 1);
            if (!half) {
                #pragma unroll
                for (int bb = 0; bb < B_BLK; ++bb) G[bb][r] = acc[bb];
            }
        }
        __syncthreads();

        // ---- phase 4: layer1 elementwise update + x-stage write ----
        if (t < G4) {
            float gi = sigmoid_(G[ubb][uu]);
            float gf = sigmoid_(G[ubb][uu +   HID]);
            float gg = tanh_   (G[ubb][uu + 2*HID]);
            float go = sigmoid_(G[ubb][uu + 3*HID]);
            c1 = gf * c1 + gi * gg;
            H1[ubb][uu] = go * tanh_(c1);
        }
        if (xldr) XS[nxt][xbb][xj] = xpre;
        __syncthreads();
    }

    // ---- epilogue: FC for the last step ----
    if (t < B_BLK) {
        float s = fcb;
        #pragma unroll
        for (int j = 0; j < HPAD; j += 4) {
            float4 hv = *(const float4*)&H1[t][j];
            float4 wv = *(const float4*)&FCW[j];
            s += wv.x*hv.x + wv.y*hv.y + wv.z*hv.z + wv.w*hv.w;
        }
        out[(size_t)(T_STEPS-1) * BATCH + b0 + t] = s;
    }
}

extern "C" void kernel_launch(void* const* d_in, const int* in_sizes, int n_in,
                              void* d_out, int out_size, void* d_ws, size_t ws_size,
                              hipStream_t stream) {
    const float* x     = (const float*)d_in[0];
    const float* w_ih0 = (const float*)d_in[1];
    const float* w_hh0 = (const float*)d_in[2];
    const float* b_ih0 = (const float*)d_in[3];
    const float* b_hh0 = (const float*)d_in[4];
    const float* w_ih1 = (const float*)d_in[5];
    const float* w_hh1 = (const float*)d_in[6];
    const float* b_ih1 = (const float*)d_in[7];
    const float* b_hh1 = (const float*)d_in[8];
    const float* fc_w  = (const float*)d_in[9];
    const float* fc_b  = (const float*)d_in[10];
    float* out = (float*)d_out;

    lstm_fused<<<dim3(BATCH / B_BLK), dim3(NT), 0, stream>>>(
        x, w_ih0, w_hh0, b_ih0, b_hh0,
        w_ih1, w_hh1, b_ih1, b_hh1, fc_w, fc_b, out);
}

// Round 3
// 382.475 us; speedup vs baseline: 6.7318x; 4.6817x over previous
//
#include <hip/hip_runtime.h>

#define T_STEPS 365
#define BATCH   2048
#define INP     9
#define HID     50
#define G4      200
#define MB      16          // batch per block (MFMA col dim)
#define NBLK    (BATCH/MB)  // 128
#define NT      512         // 8 waves
#define NW      8
#define NTILES  13          // 208 gate rows >= 200
#define TPW     2           // max tiles per wave

typedef __attribute__((ext_vector_type(8))) short short8;
typedef __attribute__((ext_vector_type(4))) float float4v;

__device__ __forceinline__ unsigned short f2bf(float v) {
    unsigned u = __builtin_bit_cast(unsigned, v);
    unsigned r = (u + 0x7FFFu + ((u >> 16) & 1u)) >> 16;
    return (unsigned short)r;
}
__device__ __forceinline__ float sig_(float x) {
    return __builtin_amdgcn_rcpf(1.f + __expf(-x));
}
__device__ __forceinline__ float tanh_(float x) {
    return 1.f - 2.f * __builtin_amdgcn_rcpf(__expf(2.f * x) + 1.f);
}

// HX buffer: [2][16 rows (batch)][128 cols bf16]
//   cols 0-49: h0, 50-58: x, 59-63: 0 | cols 64-113: h1, 114-127: 0
// XOR-swizzled to keep b128 fragment reads ~conflict-free.
__device__ __forceinline__ int hx_off(int m, int k) {   // ushort units
    return (m * 128 + k) ^ ((m & 7) << 3);
}

__global__ __launch_bounds__(NT, 1)
void lstm_mfma(const float* __restrict__ x,
               const float* __restrict__ w_ih0, const float* __restrict__ w_hh0,
               const float* __restrict__ b_ih0, const float* __restrict__ b_hh0,
               const float* __restrict__ w_ih1, const float* __restrict__ w_hh1,
               const float* __restrict__ b_ih1, const float* __restrict__ b_hh1,
               const float* __restrict__ fc_w, const float* __restrict__ fc_b,
               float* __restrict__ out)
{
    __shared__ __align__(16) unsigned short HX[2][MB * 128];
    __shared__ float FCP[NW][MB];

    const int t   = threadIdx.x;
    const int w   = t >> 6;        // wave 0..7
    const int lid = t & 63;
    const int mcol = lid & 15;     // batch column this lane supplies/owns
    const int kgrp = lid >> 4;     // 0..3
    const int kb8  = kgrp * 8;
    const int b0   = blockIdx.x * MB;
    const float fcb = fc_b[0];

    // ---- per-wave tiles: T = tt*8 + w (tt<2), valid if T < 13 ----
    // A-operand (weights) fragments: lane supplies gate-row r = T*16 + mcol,
    // interleaved row r = 4*unit + gate  ->  original row = gate*50 + unit.
    short8 wA0[TPW][2];   // layer0: K=64  = [h0(50)|x(9)|0]
    short8 wA1[TPW][4];   // layer1: K=128 = [h0(50)|0(14)|h1(50)|0(14)]
    float  bs0[TPW][4], bs1[TPW][4], fcw[TPW];
    float  c0s[TPW], c1s[TPW];

    #pragma unroll
    for (int tt = 0; tt < TPW; ++tt) {
        const int T  = tt * 8 + w;
        const bool tv = (T < NTILES);
        const int r  = T * 16 + mcol;
        const bool rv = tv && (r < G4);
        const int u  = r >> 2, g = r & 3;
        const int orig = g * HID + u;
        #pragma unroll
        for (int kt = 0; kt < 2; ++kt) {
            short8 f;
            #pragma unroll
            for (int j = 0; j < 8; ++j) {
                int k = kt * 32 + kb8 + j;
                float v = 0.f;
                if (rv) {
                    if (k < HID)            v = w_hh0[orig * HID + k];
                    else if (k < HID + INP) v = w_ih0[orig * INP + (k - HID)];
                }
                f[j] = (short)f2bf(v);
            }
            wA0[tt][kt] = f;
        }
        #pragma unroll
        for (int kt = 0; kt < 4; ++kt) {
            short8 f;
            #pragma unroll
            for (int j = 0; j < 8; ++j) {
                int k = kt * 32 + kb8 + j;
                float v = 0.f;
                if (rv) {
                    if (k < HID)                      v = w_ih1[orig * HID + k];
                    else if (k >= 64 && k < 64 + HID) v = w_hh1[orig * HID + (k - 64)];
                }
                f[j] = (short)f2bf(v);
            }
            wA1[tt][kt] = f;
        }
        const int u_lane = T * 4 + kgrp;   // unit this lane owns in D
        #pragma unroll
        for (int rr = 0; rr < 4; ++rr) {
            int row = T * 16 + kgrp * 4 + rr;          // = 4*u_lane + rr
            bool bv = tv && (row < G4);
            int uu = row >> 2, gg = row & 3;
            bs0[tt][rr] = bv ? (b_ih0[gg * HID + uu] + b_hh0[gg * HID + uu]) : 0.f;
            bs1[tt][rr] = bv ? (b_ih1[gg * HID + uu] + b_hh1[gg * HID + uu]) : 0.f;
        }
        fcw[tt] = (tv && u_lane < HID) ? fc_w[u_lane] : 0.f;
        c0s[tt] = 0.f; c1s[tt] = 0.f;
    }

    // ---- init LDS: zero both HX buffers, stage x[0] ----
    for (int i = t; i < 2 * MB * 128; i += NT) (&HX[0][0])[i] = 0;
    if (t < NW * MB) (&FCP[0][0])[t] = 0.f;
    __syncthreads();
    const bool xth = (t < MB * INP);
    const int  xm = t / INP, xj = t - xm * INP;
    if (xth) HX[0][hx_off(xm, HID + xj)] = f2bf(x[(size_t)(b0 + xm) * INP + xj]);
    __syncthreads();

    for (int step = 0; step < T_STEPS; ++step) {
        const int cur = step & 1, nxt = cur ^ 1;

        // issue next-step x load early (latency hides under layer0)
        float xv = 0.f;
        const int sp1 = step + 1;
        if (xth && sp1 < T_STEPS)
            xv = x[((size_t)sp1 * BATCH + b0 + xm) * INP + xj];

        // ---- layer 0: mfma + in-lane cell update ----
        short8 hx0 = *(const short8*)&HX[cur][hx_off(mcol, kb8)];
        short8 hx1 = *(const short8*)&HX[cur][hx_off(mcol, 32 + kb8)];
        float h0v[TPW];
        #pragma unroll
        for (int tt = 0; tt < TPW; ++tt) {
            float4v acc = {bs0[tt][0], bs0[tt][1], bs0[tt][2], bs0[tt][3]};
            acc = __builtin_amdgcn_mfma_f32_16x16x32_bf16(wA0[tt][0], hx0, acc, 0, 0, 0);
            acc = __builtin_amdgcn_mfma_f32_16x16x32_bf16(wA0[tt][1], hx1, acc, 0, 0, 0);
            float gi = sig_(acc[0]), gf = sig_(acc[1]);
            float gg = tanh_(acc[2]), go = sig_(acc[3]);
            c0s[tt] = gf * c0s[tt] + gi * gg;
            h0v[tt] = go * tanh_(c0s[tt]);
        }
        #pragma unroll
        for (int tt = 0; tt < TPW; ++tt) {
            int T = tt * 8 + w, u = T * 4 + kgrp;
            if (T < NTILES && u < HID)
                HX[nxt][hx_off(mcol, u)] = f2bf(h0v[tt]);
        }
        if (xth && sp1 < T_STEPS)
            HX[nxt][hx_off(xm, HID + xj)] = f2bf(xv);
        __syncthreads();   // B1: h0_cur (+x_next) visible

        // ---- layer 1: K = [h0_cur|x(zero-w)|pad] (nxt) ++ [h1_prev|pad] (cur) ----
        short8 a0 = *(const short8*)&HX[nxt][hx_off(mcol, kb8)];
        short8 a1 = *(const short8*)&HX[nxt][hx_off(mcol, 32 + kb8)];
        short8 a2 = *(const short8*)&HX[cur][hx_off(mcol, 64 + kb8)];
        short8 a3 = *(const short8*)&HX[cur][hx_off(mcol, 96 + kb8)];
        float fcp = 0.f;
        float h1v[TPW];
        #pragma unroll
        for (int tt = 0; tt < TPW; ++tt) {
            float4v acc = {bs1[tt][0], bs1[tt][1], bs1[tt][2], bs1[tt][3]};
            acc = __builtin_amdgcn_mfma_f32_16x16x32_bf16(wA1[tt][0], a0, acc, 0, 0, 0);
            acc = __builtin_amdgcn_mfma_f32_16x16x32_bf16(wA1[tt][1], a1, acc, 0, 0, 0);
            acc = __builtin_amdgcn_mfma_f32_16x16x32_bf16(wA1[tt][2], a2, acc, 0, 0, 0);
            acc = __builtin_amdgcn_mfma_f32_16x16x32_bf16(wA1[tt][3], a3, acc, 0, 0, 0);
            float gi = sig_(acc[0]), gf = sig_(acc[1]);
            float gg = tanh_(acc[2]), go = sig_(acc[3]);
            c1s[tt] = gf * c1s[tt] + gi * gg;
            h1v[tt] = go * tanh_(c1s[tt]);
            fcp += fcw[tt] * h1v[tt];          // FC partial in fp32
        }
        fcp += __shfl_xor(fcp, 16);
        fcp += __shfl_xor(fcp, 32);
        if (lid < MB) FCP[w][lid] = fcp;
        #pragma unroll
        for (int tt = 0; tt < TPW; ++tt) {
            int T = tt * 8 + w, u = T * 4 + kgrp;
            if (T < NTILES && u < HID)
                HX[nxt][hx_off(mcol, 64 + u)] = f2bf(h1v[tt]);
        }
        __syncthreads();   // B2: h1 + FCP visible

        if (t < MB) {
            float s = fcb;
            #pragma unroll
            for (int ww = 0; ww < NW; ++ww) s += FCP[ww][t];
            out[(size_t)step * BATCH + b0 + t] = s;
        }
    }
}

extern "C" void kernel_launch(void* const* d_in, const int* in_sizes, int n_in,
                              void* d_out, int out_size, void* d_ws, size_t ws_size,
                              hipStream_t stream) {
    const float* x     = (const float*)d_in[0];
    const float* w_ih0 = (const float*)d_in[1];
    const float* w_hh0 = (const float*)d_in[2];
    const float* b_ih0 = (const float*)d_in[3];
    const float* b_hh0 = (const float*)d_in[4];
    const float* w_ih1 = (const float*)d_in[5];
    const float* w_hh1 = (const float*)d_in[6];
    const float* b_ih1 = (const float*)d_in[7];
    const float* b_hh1 = (const float*)d_in[8];
    const float* fc_w  = (const float*)d_in[9];
    const float* fc_b  = (const float*)d_in[10];
    float* out = (float*)d_out;

    lstm_mfma<<<dim3(NBLK), dim3(NT), 0, stream>>>(
        x, w_ih0, w_hh0, b_ih0, b_hh0,
        w_ih1, w_hh1, b_ih1, b_hh1, fc_w, fc_b, out);
}

// Round 4
// 369.818 us; speedup vs baseline: 6.9622x; 1.0342x over previous
//
#include <hip/hip_runtime.h>

#define T_STEPS 365
#define BATCH   2048
#define INP     9
#define HID     50
#define MB      16          // batch per block (MFMA col dim)
#define NBLK    (BATCH/MB)  // 128
#define NT      512         // 8 waves: 0-3 layer1, 4-7 layer0
#define NTILES  13          // 208 gate rows >= 200

typedef __attribute__((ext_vector_type(8))) short short8;
typedef __attribute__((ext_vector_type(4))) float float4v;

__device__ __forceinline__ unsigned short f2bf(float v) {
    unsigned u = __builtin_bit_cast(unsigned, v);
    unsigned r = (u + 0x7FFFu + ((u >> 16) & 1u)) >> 16;
    return (unsigned short)r;
}
__device__ __forceinline__ float sig_(float x) {
    return __builtin_amdgcn_rcpf(1.f + __expf(-x));
}
__device__ __forceinline__ float tanh_(float x) {
    return 1.f - 2.f * __builtin_amdgcn_rcpf(__expf(2.f * x) + 1.f);
}

// HX[p]: [16 batch rows][128 bf16 cols]: 0-49 h0 | 50-58 x | 59-63 zero | 64-113 h1 | 114-127 zero
// XOR swizzle keeps b128 fragment reads conflict-free (2-way max).
__device__ __forceinline__ int hx_off(int m, int k) {   // ushort units
    return (m * 128 + k) ^ ((m & 7) << 3);
}

// Layer-pipelined LSTM: phase t computes layer0(t) on waves 4-7 CONCURRENTLY
// with layer1(t-1) on waves 0-3; ONE barrier per phase. All reads hit
// buf[(t+1)&1], all writes go to buf[t&1].
__global__ __launch_bounds__(NT, 2)
void lstm_pipe(const float* __restrict__ x,
               const float* __restrict__ w_ih0, const float* __restrict__ w_hh0,
               const float* __restrict__ b_ih0, const float* __restrict__ b_hh0,
               const float* __restrict__ w_ih1, const float* __restrict__ w_hh1,
               const float* __restrict__ b_ih1, const float* __restrict__ b_hh1,
               const float* __restrict__ fc_w, const float* __restrict__ fc_b,
               float* __restrict__ out)
{
    __shared__ __align__(16) unsigned short HX[2][MB * 128];
    __shared__ float FCP[2][4][MB];   // double-buffered FC partials per L1 wave

    const int t    = threadIdx.x;
    const int w    = t >> 6;
    const int lid  = t & 63;
    const int mcol = lid & 15;
    const int kgrp = lid >> 4;
    const int kb8  = kgrp * 8;
    const int b0   = blockIdx.x * MB;
    const bool isL1 = (w < 4);
    const int v    = isL1 ? w : (w - 4);     // role-wave index 0..3
    const float fcb = fc_b[0];

    // ---- weights into registers: wave v owns tiles {v, v+4, v+8, v+12} < 13 ----
    // gate-interleaved rows: tile row r = 4*unit + gate  ->  original row = gate*50 + unit
    short8 wA[4][4];
    float  bs[4][4], fcw[4], cst[4];
    const float* bih = isL1 ? b_ih1 : b_ih0;
    const float* bhh = isL1 ? b_hh1 : b_hh0;

    #pragma unroll
    for (int tt = 0; tt < 4; ++tt) {
        const int T  = v + 4 * tt;
        const bool tv = (T < NTILES);
        const int r  = T * 16 + mcol;
        const bool rv = tv && (r < 4 * HID);
        const int u_r = r >> 2, g_r = r & 3;
        const int orig = g_r * HID + u_r;
        if (isL1) {
            // layer1 K=128: [w_ih1 on h0(50) | 0 | w_hh1 on h1(50) | 0]
            #pragma unroll
            for (int kt = 0; kt < 4; ++kt) {
                short8 f;
                #pragma unroll
                for (int j = 0; j < 8; ++j) {
                    int k = kt * 32 + kb8 + j;
                    float val = 0.f;
                    if (rv) {
                        if (k < HID)                      val = w_ih1[orig * HID + k];
                        else if (k >= 64 && k < 64 + HID) val = w_hh1[orig * HID + (k - 64)];
                    }
                    f[j] = (short)f2bf(val);
                }
                wA[tt][kt] = f;
            }
        } else {
            // layer0 K=64: [w_hh0 on h0(50) | w_ih0 on x(9) | 0]
            #pragma unroll
            for (int kt = 0; kt < 2; ++kt) {
                short8 f;
                #pragma unroll
                for (int j = 0; j < 8; ++j) {
                    int k = kt * 32 + kb8 + j;
                    float val = 0.f;
                    if (rv) {
                        if (k < HID)            val = w_hh0[orig * HID + k];
                        else if (k < HID + INP) val = w_ih0[orig * INP + (k - HID)];
                    }
                    f[j] = (short)f2bf(val);
                }
                wA[tt][kt] = f;
            }
            wA[tt][2] = short8{}; wA[tt][3] = short8{};
        }
        const int u_lane = T * 4 + kgrp;
        #pragma unroll
        for (int rr = 0; rr < 4; ++rr) {
            int row = T * 16 + kgrp * 4 + rr;   // = 4*u_lane + rr
            bool bvv = tv && (row < 4 * HID);
            int uu = row >> 2;
            bs[tt][rr] = bvv ? (bih[rr * HID + uu] + bhh[rr * HID + uu]) : 0.f;
        }
        fcw[tt] = (isL1 && tv && u_lane < HID) ? fc_w[u_lane] : 0.f;
        cst[tt] = 0.f;
    }

    // ---- x-loader identity (on layer0 waves 4,5,6): 144 values ----
    int xi = -1;
    if (w == 4) xi = lid;
    else if (w == 5) xi = 64 + lid;
    else if (w == 6 && lid < 16) xi = 128 + lid;
    const bool xact = (xi >= 0 && xi < MB * INP);
    const int xm = xact ? xi / INP : 0, xj = xact ? xi % INP : 0;

    // ---- init LDS ----
    for (int i = t; i < 2 * MB * 128; i += NT) (&HX[0][0])[i] = 0;
    if (t < 2 * 4 * MB) (&FCP[0][0][0])[t] = 0.f;
    __syncthreads();
    float xreg = 0.f;
    if (xact) {
        // x(0) into buf[1] (phase 0 reads cur = 1); xreg <- x(1)
        HX[1][hx_off(xm, HID + xj)] = f2bf(x[(size_t)(b0 + xm) * INP + xj]);
        xreg = x[((size_t)BATCH + b0 + xm) * INP + xj];
    }
    __syncthreads();

    for (int ph = 0; ph < T_STEPS + 2; ++ph) {
        const int cur = (ph + 1) & 1, nxt = ph & 1;

        short8 f0 = *(const short8*)&HX[cur][hx_off(mcol, kb8)];
        short8 f1 = *(const short8*)&HX[cur][hx_off(mcol, 32 + kb8)];

        if (isL1) {
            // ---- layer1: h1(ph-1) from h0(ph-1), h1(ph-2); FC partials ----
            if (ph >= 1 && ph <= T_STEPS) {
                short8 f2 = *(const short8*)&HX[cur][hx_off(mcol, 64 + kb8)];
                short8 f3 = *(const short8*)&HX[cur][hx_off(mcol, 96 + kb8)];
                float h1v[4];
                float fcp = 0.f;
                #pragma unroll
                for (int tt = 0; tt < 4; ++tt) {
                    const int T = v + 4 * tt;
                    if (T < NTILES) {
                        float4v acc = {bs[tt][0], bs[tt][1], bs[tt][2], bs[tt][3]};
                        acc = __builtin_amdgcn_mfma_f32_16x16x32_bf16(wA[tt][0], f0, acc, 0, 0, 0);
                        acc = __builtin_amdgcn_mfma_f32_16x16x32_bf16(wA[tt][1], f1, acc, 0, 0, 0);
                        acc = __builtin_amdgcn_mfma_f32_16x16x32_bf16(wA[tt][2], f2, acc, 0, 0, 0);
                        acc = __builtin_amdgcn_mfma_f32_16x16x32_bf16(wA[tt][3], f3, acc, 0, 0, 0);
                        float gi = sig_(acc[0]), gf = sig_(acc[1]);
                        float gg = tanh_(acc[2]), go = sig_(acc[3]);
                        cst[tt] = gf * cst[tt] + gi * gg;
                        h1v[tt] = go * tanh_(cst[tt]);
                        fcp += fcw[tt] * h1v[tt];
                    }
                }
                #pragma unroll
                for (int tt = 0; tt < 4; ++tt) {
                    const int T = v + 4 * tt, u = T * 4 + kgrp;
                    if (T < NTILES && u < HID)
                        HX[nxt][hx_off(mcol, 64 + u)] = f2bf(h1v[tt]);
                }
                fcp += __shfl_xor(fcp, 16);
                fcp += __shfl_xor(fcp, 32);
                if (lid < MB) FCP[ph & 1][v][lid] = fcp;
            }
        } else {
            // ---- layer0: h0(ph) from h0(ph-1), x(ph) ----
            if (ph < T_STEPS) {
                float h0v[4];
                #pragma unroll
                for (int tt = 0; tt < 4; ++tt) {
                    const int T = v + 4 * tt;
                    if (T < NTILES) {
                        float4v acc = {bs[tt][0], bs[tt][1], bs[tt][2], bs[tt][3]};
                        acc = __builtin_amdgcn_mfma_f32_16x16x32_bf16(wA[tt][0], f0, acc, 0, 0, 0);
                        acc = __builtin_amdgcn_mfma_f32_16x16x32_bf16(wA[tt][1], f1, acc, 0, 0, 0);
                        float gi = sig_(acc[0]), gf = sig_(acc[1]);
                        float gg = tanh_(acc[2]), go = sig_(acc[3]);
                        cst[tt] = gf * cst[tt] + gi * gg;
                        h0v[tt] = go * tanh_(cst[tt]);
                    }
                }
                #pragma unroll
                for (int tt = 0; tt < 4; ++tt) {
                    const int T = v + 4 * tt, u = T * 4 + kgrp;
                    if (T < NTILES && u < HID)
                        HX[nxt][hx_off(mcol, u)] = f2bf(h0v[tt]);
                }
            }
            // ---- x staging: write x(ph+1) to nxt, prefetch x(ph+2) ----
            if (xact) {
                if (ph + 1 < T_STEPS) HX[nxt][hx_off(xm, HID + xj)] = f2bf(xreg);
                if (ph + 2 < T_STEPS) xreg = x[((size_t)(ph + 2) * BATCH + b0 + xm) * INP + xj];
            }
            // ---- out writer (wave 7): out[ph-2] from FCP written at ph-1 ----
            if (w == 7 && lid < MB && ph >= 2) {
                const int rp = (ph - 1) & 1;
                float s = fcb + FCP[rp][0][lid] + FCP[rp][1][lid]
                              + FCP[rp][2][lid] + FCP[rp][3][lid];
                out[(size_t)(ph - 2) * BATCH + b0 + lid] = s;
            }
        }
        __syncthreads();
    }
}

extern "C" void kernel_launch(void* const* d_in, const int* in_sizes, int n_in,
                              void* d_out, int out_size, void* d_ws, size_t ws_size,
                              hipStream_t stream) {
    const float* x     = (const float*)d_in[0];
    const float* w_ih0 = (const float*)d_in[1];
    const float* w_hh0 = (const float*)d_in[2];
    const float* b_ih0 = (const float*)d_in[3];
    const float* b_hh0 = (const float*)d_in[4];
    const float* w_ih1 = (const float*)d_in[5];
    const float* w_hh1 = (const float*)d_in[6];
    const float* b_ih1 = (const float*)d_in[7];
    const float* b_hh1 = (const float*)d_in[8];
    const float* fc_w  = (const float*)d_in[9];
    const float* fc_b  = (const float*)d_in[10];
    float* out = (float*)d_out;

    lstm_pipe<<<dim3(NBLK), dim3(NT), 0, stream>>>(
        x, w_ih0, w_hh0, b_ih0, b_hh0,
        w_ih1, w_hh1, b_ih1, b_hh1, fc_w, fc_b, out);
}

// Round 5
// 354.197 us; speedup vs baseline: 7.2692x; 1.0441x over previous
//
#include <hip/hip_runtime.h>

#define T_STEPS 365
#define BATCH   2048
#define INP     9
#define HID     50
#define MB      16          // batch per block (MFMA col dim)
#define NBLK    (BATCH/MB)  // 128
#define NT      1024        // 16 waves: 0-7 layer1, 8-15 layer0
#define NTILES  13          // 208 gate rows >= 200
#define TPW     2

typedef __attribute__((ext_vector_type(8))) short short8;
typedef __attribute__((ext_vector_type(4))) float float4v;

__device__ __forceinline__ unsigned short f2bf(float v) {
    unsigned u = __builtin_bit_cast(unsigned, v);
    unsigned r = (u + 0x7FFFu + ((u >> 16) & 1u)) >> 16;
    return (unsigned short)r;
}
__device__ __forceinline__ float sig_(float x) {
    return __builtin_amdgcn_rcpf(1.f + __expf(-x));
}
__device__ __forceinline__ float tanh_(float x) {
    return 1.f - 2.f * __builtin_amdgcn_rcpf(__expf(2.f * x) + 1.f);
}

// HX[p]: [16 batch rows][128 bf16 cols]: 0-49 h0 | 50-58 x | 59-63 zero | 64-113 h1 | 114-127 zero
// XOR swizzle keeps b128 fragment reads low-conflict.
__device__ __forceinline__ int hx_off(int m, int k) {   // ushort units
    return (m * 128 + k) ^ ((m & 7) << 3);
}

// Layer-pipelined LSTM, 16 waves: phase t runs layer0(t) on waves 8-15
// concurrently with layer1(t-1) on waves 0-7; ONE barrier per phase.
// 2 tiles/wave -> short chains; 4 waves/SIMD -> stall overlap.
__global__ __launch_bounds__(NT, 4)
void lstm_pipe16(const float* __restrict__ x,
                 const float* __restrict__ w_ih0, const float* __restrict__ w_hh0,
                 const float* __restrict__ b_ih0, const float* __restrict__ b_hh0,
                 const float* __restrict__ w_ih1, const float* __restrict__ w_hh1,
                 const float* __restrict__ b_ih1, const float* __restrict__ b_hh1,
                 const float* __restrict__ fc_w, const float* __restrict__ fc_b,
                 float* __restrict__ out)
{
    __shared__ __align__(16) unsigned short HX[2][MB * 128];
    __shared__ float FCP[2][8][MB];   // double-buffered FC partials per L1 wave

    const int t    = threadIdx.x;
    const int w    = t >> 6;
    const int lid  = t & 63;
    const int mcol = lid & 15;
    const int kgrp = lid >> 4;
    const int kb8  = kgrp * 8;
    const int b0   = blockIdx.x * MB;
    const bool isL1 = (w < 8);
    const int v    = w & 7;                  // role-wave index 0..7
    const float fcb = fc_b[0];

    // ---- weights: wave v owns tiles {v, v+8} (valid if < 13) ----
    // gate-interleaved rows: tile row r = 4*unit + gate  ->  original row = gate*50 + unit
    short8 wA[TPW][4];
    float  bs[TPW][4], fcw[TPW], cst[TPW];
    const float* bih = isL1 ? b_ih1 : b_ih0;
    const float* bhh = isL1 ? b_hh1 : b_hh0;

    #pragma unroll
    for (int tt = 0; tt < TPW; ++tt) {
        const int T  = v + 8 * tt;
        const bool tv = (T < NTILES);
        const int r  = T * 16 + mcol;
        const bool rv = tv && (r < 4 * HID);
        const int u_r = r >> 2, g_r = r & 3;
        const int orig = g_r * HID + u_r;
        #pragma unroll
        for (int kt = 0; kt < 4; ++kt) {
            short8 f;
            #pragma unroll
            for (int j = 0; j < 8; ++j) {
                int k = kt * 32 + kb8 + j;
                float val = 0.f;
                if (rv) {
                    if (isL1) {
                        if (k < HID)                      val = w_ih1[orig * HID + k];
                        else if (k >= 64 && k < 64 + HID) val = w_hh1[orig * HID + (k - 64)];
                    } else {
                        if (k < HID)            val = w_hh0[orig * HID + k];
                        else if (k < HID + INP) val = w_ih0[orig * INP + (k - HID)];
                    }
                }
                f[j] = (short)f2bf(val);
            }
            wA[tt][kt] = f;
        }
        const int u_lane = T * 4 + kgrp;
        #pragma unroll
        for (int rr = 0; rr < 4; ++rr) {
            int row = T * 16 + kgrp * 4 + rr;   // = 4*u_lane + rr
            bool bvv = tv && (row < 4 * HID);
            int uu = row >> 2;
            bs[tt][rr] = bvv ? (bih[rr * HID + uu] + bhh[rr * HID + uu]) : 0.f;
        }
        fcw[tt] = (isL1 && tv && u_lane < HID) ? fc_w[u_lane] : 0.f;
        cst[tt] = 0.f;
    }

    // ---- x-loader identity (L0 waves 8,9,10): 144 values ----
    int xi = -1;
    if (w == 8) xi = lid;
    else if (w == 9) xi = 64 + lid;
    else if (w == 10 && lid < 16) xi = 128 + lid;
    const bool xact = (xi >= 0 && xi < MB * INP);
    const int xm = xact ? xi / INP : 0, xj = xact ? xi % INP : 0;

    // ---- init LDS ----
    for (int i = t; i < 2 * MB * 128; i += NT) (&HX[0][0])[i] = 0;
    if (t < 2 * 8 * MB) (&FCP[0][0][0])[t] = 0.f;
    __syncthreads();
    float xreg = 0.f;
    if (xact) {
        // x(0) into buf[1] (phase 0 reads cur = 1); xreg <- x(1)
        HX[1][hx_off(xm, HID + xj)] = f2bf(x[(size_t)(b0 + xm) * INP + xj]);
        xreg = x[((size_t)BATCH + b0 + xm) * INP + xj];
    }
    __syncthreads();

    for (int ph = 0; ph < T_STEPS + 2; ++ph) {
        const int cur = (ph + 1) & 1, nxt = ph & 1;

        short8 f0 = *(const short8*)&HX[cur][hx_off(mcol, kb8)];
        short8 f1 = *(const short8*)&HX[cur][hx_off(mcol, 32 + kb8)];

        if (isL1) {
            // ---- layer1: h1(ph-1) from h0(ph-1), h1(ph-2); FC partials ----
            if (ph >= 1 && ph <= T_STEPS) {
                short8 f2 = *(const short8*)&HX[cur][hx_off(mcol, 64 + kb8)];
                short8 f3 = *(const short8*)&HX[cur][hx_off(mcol, 96 + kb8)];
                float h1v[TPW];
                float fcp = 0.f;
                #pragma unroll
                for (int tt = 0; tt < TPW; ++tt) {
                    const int T = v + 8 * tt;
                    if (T < NTILES) {
                        // two independent 2-chains, summed at the end
                        float4v accA = {bs[tt][0], bs[tt][1], bs[tt][2], bs[tt][3]};
                        float4v accB = {0.f, 0.f, 0.f, 0.f};
                        accA = __builtin_amdgcn_mfma_f32_16x16x32_bf16(wA[tt][0], f0, accA, 0, 0, 0);
                        accB = __builtin_amdgcn_mfma_f32_16x16x32_bf16(wA[tt][2], f2, accB, 0, 0, 0);
                        accA = __builtin_amdgcn_mfma_f32_16x16x32_bf16(wA[tt][1], f1, accA, 0, 0, 0);
                        accB = __builtin_amdgcn_mfma_f32_16x16x32_bf16(wA[tt][3], f3, accB, 0, 0, 0);
                        float a0 = accA[0] + accB[0], a1 = accA[1] + accB[1];
                        float a2 = accA[2] + accB[2], a3 = accA[3] + accB[3];
                        float gi = sig_(a0), gf = sig_(a1);
                        float gg = tanh_(a2), go = sig_(a3);
                        cst[tt] = gf * cst[tt] + gi * gg;
                        h1v[tt] = go * tanh_(cst[tt]);
                        fcp += fcw[tt] * h1v[tt];
                    }
                }
                #pragma unroll
                for (int tt = 0; tt < TPW; ++tt) {
                    const int T = v + 8 * tt, u = T * 4 + kgrp;
                    if (T < NTILES && u < HID)
                        HX[nxt][hx_off(mcol, 64 + u)] = f2bf(h1v[tt]);
                }
                fcp += __shfl_xor(fcp, 16);
                fcp += __shfl_xor(fcp, 32);
                if (lid < MB) FCP[ph & 1][v][lid] = fcp;
            }
        } else {
            // ---- layer0: h0(ph) from h0(ph-1), x(ph) ----
            if (ph < T_STEPS) {
                float h0v[TPW];
                #pragma unroll
                for (int tt = 0; tt < TPW; ++tt) {
                    const int T = v + 8 * tt;
                    if (T < NTILES) {
                        float4v acc = {bs[tt][0], bs[tt][1], bs[tt][2], bs[tt][3]};
                        acc = __builtin_amdgcn_mfma_f32_16x16x32_bf16(wA[tt][0], f0, acc, 0, 0, 0);
                        acc = __builtin_amdgcn_mfma_f32_16x16x32_bf16(wA[tt][1], f1, acc, 0, 0, 0);
                        float gi = sig_(acc[0]), gf = sig_(acc[1]);
                        float gg = tanh_(acc[2]), go = sig_(acc[3]);
                        cst[tt] = gf * cst[tt] + gi * gg;
                        h0v[tt] = go * tanh_(cst[tt]);
                    }
                }
                #pragma unroll
                for (int tt = 0; tt < TPW; ++tt) {
                    const int T = v + 8 * tt, u = T * 4 + kgrp;
                    if (T < NTILES && u < HID)
                        HX[nxt][hx_off(mcol, u)] = f2bf(h0v[tt]);
                }
            }
            // ---- x staging: write x(ph+1) to nxt, prefetch x(ph+2) ----
            if (xact) {
                if (ph + 1 < T_STEPS) HX[nxt][hx_off(xm, HID + xj)] = f2bf(xreg);
                if (ph + 2 < T_STEPS) xreg = x[((size_t)(ph + 2) * BATCH + b0 + xm) * INP + xj];
            }
            // ---- out writer (wave 15): out[ph-2] from FCP written at ph-1 ----
            if (w == 15 && lid < MB && ph >= 2) {
                const int rp = (ph - 1) & 1;
                float s = fcb;
                #pragma unroll
                for (int ww = 0; ww < 8; ++ww) s += FCP[rp][ww][lid];
                out[(size_t)(ph - 2) * BATCH + b0 + lid] = s;
            }
        }
        __syncthreads();
    }
}

extern "C" void kernel_launch(void* const* d_in, const int* in_sizes, int n_in,
                              void* d_out, int out_size, void* d_ws, size_t ws_size,
                              hipStream_t stream) {
    const float* x     = (const float*)d_in[0];
    const float* w_ih0 = (const float*)d_in[1];
    const float* w_hh0 = (const float*)d_in[2];
    const float* b_ih0 = (const float*)d_in[3];
    const float* b_hh0 = (const float*)d_in[4];
    const float* w_ih1 = (const float*)d_in[5];
    const float* w_hh1 = (const float*)d_in[6];
    const float* b_ih1 = (const float*)d_in[7];
    const float* b_hh1 = (const float*)d_in[8];
    const float* fc_w  = (const float*)d_in[9];
    const float* fc_b  = (const float*)d_in[10];
    float* out = (float*)d_out;

    lstm_pipe16<<<dim3(NBLK), dim3(NT), 0, stream>>>(
        x, w_ih0, w_hh0, b_ih0, b_hh0,
        w_ih1, w_hh1, b_ih1, b_hh1, fc_w, fc_b, out);
}